// Round 1
// baseline (1740.845 us; speedup 1.0000x reference)
//
#include <hip/hip_runtime.h>
#include <hip/hip_bf16.h>
#include <cstdint>
#include <cstddef>

#define NTHREADS 1024
#define BB 16
#define NN 256
#define EPAD_TOTAL 33280  // sum over d of roundup4(256-d)

typedef unsigned char u8;

// Mask arrays may arrive as bool (1 byte), int32, or float32 depending on the
// harness upload convention. Detect on device: maskspan[0,0,1] == 1 always
// (lens >= 128). Byte storage -> byte1 == 1; 4-byte storage -> byte1 == 0.
// For 4-byte storage, reading as int and testing != 0 works for both int32
// and float32 (bit pattern of nonzero float is nonzero int).
__device__ __forceinline__ bool mask_val(const void* p, size_t idx, bool isbyte) {
  return isbyte ? (((const u8*)p)[idx] != 0) : (((const int*)p)[idx] != 0);
}

__device__ __forceinline__ float score_val(float2 v, const void* sind, size_t cell,
                                           int run, bool isbyte) {
  if (run == 0) {
    // ob = spans_ind ? logaddexp(NEG, sl1) : logaddexp(sl0, NEG) == selected channel
    return mask_val(sind, cell, isbyte) ? v.y : v.x;
  } else {
    // allp = logaddexp(sl0, sl1)
    float m = fmaxf(v.x, v.y);
    return m + log1pf(__expf(-fabsf(v.x - v.y)));
  }
}

extern "C" __global__ void __launch_bounds__(NTHREADS, 1)
cyk_kernel(const float2* __restrict__ slog, const void* __restrict__ sind,
           const void* __restrict__ mspan, float* __restrict__ wsv) {
  // Exp-space chart, diagonal-major, each diagonal 16B-aligned.
  __shared__ __align__(16) float E[EPAD_TOTAL];
  __shared__ float Mar[NN];     // per-diagonal log offset: alpha = log(E) + Mar[d]
  __shared__ float ftab[NN];    // per-width split scale factors
  __shared__ int   tabR[NN];    // per-width right-operand base offsets
  __shared__ int   off4[NN + 1];
  __shared__ float scratch[NTHREADS / 64];

  const int b = blockIdx.x >> 1;
  const int run = blockIdx.x & 1;
  const int tid = threadIdx.x;
  const bool isbyte = ((const u8*)mspan)[1] != 0;
  const size_t sbase = (size_t)b * (NN * NN);

  // sentence length = count of maskspan[b, 0, j]
  int pred = 0;
  if (tid < NN) pred = mask_val(mspan, sbase + tid, isbyte) ? 1 : 0;
  const int len = __syncthreads_count(pred);

  // padded diagonal offset table
  if (tid == 0) {
    int a = 0;
    for (int d2 = 0; d2 < NN; ++d2) { off4[d2] = a; a += (NN - d2 + 3) & ~3; }
    off4[NN] = a;
  }
  // zero chart (pad regions must be 0; overreads into pads then contribute 0)
  for (int k = tid; k < EPAD_TOTAL; k += NTHREADS) E[k] = 0.0f;
  __syncthreads();

  // ---- diagonal 0 (width 1) ----
  float a0 = -3.0e38f;
  if (tid < len) {
    size_t cell = sbase + (size_t)tid * NN + tid;
    a0 = score_val(slog[cell], sind, cell, run, isbyte);
  }
  float wm = a0;
  #pragma unroll
  for (int o = 1; o < 64; o <<= 1) wm = fmaxf(wm, __shfl_xor(wm, o, 64));
  if ((tid & 63) == 0) scratch[tid >> 6] = wm;
  __syncthreads();
  float M0 = scratch[0];
  #pragma unroll
  for (int k2 = 1; k2 < NTHREADS / 64; ++k2) M0 = fmaxf(M0, scratch[k2]);
  if (tid < len) E[tid] = __expf(a0 - M0);
  if (tid == 0) Mar[0] = M0;
  __syncthreads();

  // ---- widths 2..len ----
  for (int w = 2; w <= len; ++w) {
    const int d = w - 1;
    const int C = len - w + 1;   // number of cells on this diagonal
    const int S = w - 1;         // number of splits per cell
    const float Gw = Mar[w - 2] + Mar[0];

    // phase 1: per-split factor table (exponent in f64: exact offset cancellation)
    if (tid < S) {
      const int u = tid, vd = w - 2 - u;
      double ex = (double)Mar[u] + (double)Mar[vd] - (double)Gw;
      ftab[u] = __expf((float)ex);
      tabR[u] = off4[vd] + u + 1;
    }
    __syncthreads();

    // phase 2: accumulate S_c = sum_u f_u * E_u[c] * E_v[c+u+1]
    const int chunks = (C + 3) >> 2;
    int G;
    {
      int i4  = ((chunks + 255) >> 8) * ((S + 3) >> 2);
      int i16 = ((chunks + 63) >> 6) * ((S + 15) >> 4);
      int i64v = ((chunks + 15) >> 4) * ((S + 63) >> 6);
      G = 4; int bi = i4;
      if (i16 < bi) { bi = i16; G = 16; }
      if (i64v < bi) { G = 64; }
    }
    const int r = tid & (G - 1);
    const int grp = tid / G;
    const int NGr = NTHREADS / G;
    const int dOff = off4[d];
    float vmaxl = 0.0f;

    for (int ch = grp; ch < chunks; ch += NGr) {
      const int c0 = ch << 2;
      float sc0 = 0.f, sc1 = 0.f, sc2 = 0.f, sc3 = 0.f;
      if (r == 0) {  // prefetch span scores for the 4 cells (used after the u-loop)
        if (c0 + 0 < C) { size_t cl = sbase + (size_t)(c0 + 0) * NN + (c0 + 0 + d); sc0 = score_val(slog[cl], sind, cl, run, isbyte); }
        if (c0 + 1 < C) { size_t cl = sbase + (size_t)(c0 + 1) * NN + (c0 + 1 + d); sc1 = score_val(slog[cl], sind, cl, run, isbyte); }
        if (c0 + 2 < C) { size_t cl = sbase + (size_t)(c0 + 2) * NN + (c0 + 2 + d); sc2 = score_val(slog[cl], sind, cl, run, isbyte); }
        if (c0 + 3 < C) { size_t cl = sbase + (size_t)(c0 + 3) * NN + (c0 + 3 + d); sc3 = score_val(slog[cl], sind, cl, run, isbyte); }
      }
      float s0 = 0.f, s1 = 0.f, s2 = 0.f, s3 = 0.f;
      for (int u = r; u < S; u += G) {
        const float fu = ftab[u];
        const int aL = off4[u] + c0;
        const int aR = tabR[u] + c0;
        const float4 L = *(const float4*)&E[aL];
        const float R0 = E[aR + 0], R1 = E[aR + 1], R2 = E[aR + 2], R3 = E[aR + 3];
        s0 = fmaf(fu * L.x, R0, s0);
        s1 = fmaf(fu * L.y, R1, s1);
        s2 = fmaf(fu * L.z, R2, s2);
        s3 = fmaf(fu * L.w, R3, s3);
      }
      #pragma unroll
      for (int o = 1; o < 64; o <<= 1) {
        if (o < G) {
          s0 += __shfl_xor(s0, o, 64);
          s1 += __shfl_xor(s1, o, 64);
          s2 += __shfl_xor(s2, o, 64);
          s3 += __shfl_xor(s3, o, 64);
        }
      }
      if (r == 0) {  // write raw V (normalized in phase 3)
        float V;
        if (c0 + 0 < C) { V = s0 * __expf(sc0); E[dOff + c0 + 0] = V; vmaxl = fmaxf(vmaxl, V); }
        if (c0 + 1 < C) { V = s1 * __expf(sc1); E[dOff + c0 + 1] = V; vmaxl = fmaxf(vmaxl, V); }
        if (c0 + 2 < C) { V = s2 * __expf(sc2); E[dOff + c0 + 2] = V; vmaxl = fmaxf(vmaxl, V); }
        if (c0 + 3 < C) { V = s3 * __expf(sc3); E[dOff + c0 + 3] = V; vmaxl = fmaxf(vmaxl, V); }
      }
    }
    #pragma unroll
    for (int o = 1; o < 64; o <<= 1) vmaxl = fmaxf(vmaxl, __shfl_xor(vmaxl, o, 64));
    if ((tid & 63) == 0) scratch[tid >> 6] = vmaxl;
    __syncthreads();

    // phase 3: normalize diagonal, record offset
    float R = scratch[0];
    #pragma unroll
    for (int k2 = 1; k2 < NTHREADS / 64; ++k2) R = fmaxf(R, scratch[k2]);
    R = fmaxf(R, 1e-35f);
    const float invR = 1.0f / R;
    for (int c = tid; c < C; c += NTHREADS) E[dOff + c] *= invR;
    if (tid == 0) Mar[d] = __logf(R) + Gw;
    __syncthreads();
  }

  // alpha[0, len-1] = Mar[len-1] + log(E=1)
  if (tid == 0) {
    wsv[run * BB + b] = Mar[len - 1];
    if (run == 0) wsv[2 * BB + b] = (float)len;
  }
}

extern "C" __global__ void loss_kernel(const float* __restrict__ wsv, float* __restrict__ out) {
  const int t = threadIdx.x;
  float diff = 0.0f, ln = 0.0f;
  if (t < BB) { diff = wsv[BB + t] - wsv[t]; ln = wsv[2 * BB + t]; }
  #pragma unroll
  for (int o = 1; o < 64; o <<= 1) {
    diff += __shfl_xor(diff, o, 64);
    ln += __shfl_xor(ln, o, 64);
  }
  if (t == 0) out[0] = diff / ln;
}

extern "C" void kernel_launch(void* const* d_in, const int* in_sizes, int n_in,
                              void* d_out, int out_size, void* d_ws, size_t ws_size,
                              hipStream_t stream) {
  const float2* slog = (const float2*)d_in[0];
  const void* sind = d_in[1];
  const void* mspan = d_in[2];
  // d_in[3] (span_mask) not needed: within-sentence upper-triangle cells are
  // never masked, and out-of-sentence cells cannot influence alpha[0, len-1].
  float* wsv = (float*)d_ws;
  cyk_kernel<<<dim3(BB * 2), dim3(NTHREADS), 0, stream>>>(slog, sind, mspan, wsv);
  loss_kernel<<<dim3(1), dim3(64), 0, stream>>>(wsv, (float*)d_out);
}

// Round 3
// 626.871 us; speedup vs baseline: 2.7770x; 2.7770x over previous
//
#include <hip/hip_runtime.h>
#include <hip/hip_bf16.h>
#include <cstdint>
#include <cstddef>

#define NTHREADS 1024
#define NWAVES 16
#define BB 16
#define NN 256
#define EPAD_TOTAL 33280   // sum over d of roundup4(256-d)
#define PSTRIDE 68         // Part row stride (64 + 4 pad)

typedef unsigned char u8;

// Mask arrays may arrive as bool (1 byte), int32, or float32. Detect on
// device: maskspan[0,0,1] == 1 always (lens >= 128). Byte storage -> byte1
// == 1; 4-byte storage -> byte1 == 0 (nonzero int/float bit pattern test).
__device__ __forceinline__ bool mask_val(const void* p, size_t idx, bool isbyte) {
  return isbyte ? (((const u8*)p)[idx] != 0) : (((const int*)p)[idx] != 0);
}

__device__ __forceinline__ float score_val(float2 v, const void* sind, size_t cell,
                                           int run, bool isbyte) {
  if (run == 0) return mask_val(sind, cell, isbyte) ? v.y : v.x;  // ob
  float m = fmaxf(v.x, v.y);                                      // allp
  return m + __logf(1.f + __expf(-fabsf(v.x - v.y)));
}

// prefix of padded diagonal sizes: Fpad(M) = sum_{j=1..M} ((j+3)&~3)
__device__ __forceinline__ int Fpad(int M) {
  int f = M >> 2, r = M & 3;
  return 8*f*f + 8*f + 4*r*(f+1);
}

extern "C" __global__ void __launch_bounds__(NTHREADS, 1)
cyk_kernel(const float2* __restrict__ slog, const void* __restrict__ sind,
           const void* __restrict__ mspan, float* __restrict__ wsv) {
  // Exp-space chart, diagonal-major, each diagonal 16B-aligned.
  // alpha(d,c) = log(E[off4[d]+c]) + Mar[d]; Mar is a deterministic schedule:
  // Mar[d] = Mar[d-1] + log(Rmax[d-1])  (== true max alpha of diag d-1),
  // so stored magnitudes stay ~exp(per-width delta) without a normalize pass.
  __shared__ __align__(16) float E[EPAD_TOTAL];
  __shared__ __align__(16) float4 ft4[NN];   // {f_u, bits(aL), bits(aR), -}
  __shared__ float Mar[NN];
  __shared__ unsigned RmaxU[NN];
  __shared__ int off4[NN + 1];
  __shared__ float Part[NWAVES * PSTRIDE];
  __shared__ float scratch[NWAVES];

  const int b = blockIdx.x >> 1;
  const int run = blockIdx.x & 1;
  const int tid = threadIdx.x;
  const int lane = tid & 63;
  const int q = tid >> 6;
  const bool isbyte = ((const u8*)mspan)[1] != 0;
  const size_t sbase = (size_t)b * (NN * NN);

  // sentence length
  int pred = 0;
  if (tid < NN) pred = mask_val(mspan, sbase + tid, isbyte) ? 1 : 0;
  const int len = __syncthreads_count(pred);

  if (tid <= NN) off4[tid] = Fpad(NN) - Fpad(NN - tid);
  for (int k = tid; k < EPAD_TOTAL; k += NTHREADS) E[k] = 0.f;
  if (tid < NN) RmaxU[tid] = 0u;
  __syncthreads();

  // ---- diagonal 0 ----
  float a0 = -3.0e38f;
  if (tid < len) {
    size_t cell = sbase + (size_t)tid * NN + tid;
    a0 = score_val(slog[cell], sind, cell, run, isbyte);
  }
  float wm = a0;
  #pragma unroll
  for (int o = 1; o < 64; o <<= 1) wm = fmaxf(wm, __shfl_xor(wm, o, 64));
  if (lane == 0) scratch[q] = wm;
  __syncthreads();
  float M0 = scratch[0];
  #pragma unroll
  for (int k = 1; k < NWAVES; ++k) M0 = fmaxf(M0, scratch[k]);
  if (tid < len) E[tid] = __expf(a0 - M0);
  if (tid == 0) { Mar[0] = M0; RmaxU[0] = __float_as_uint(1.0f); }
  double MarD = (double)M0;   // tid0's exact Mar chain
  __syncthreads();

  float myScore = 0.f;        // prefetched span score, carried across phases

  for (int w = 2; w <= len; ++w) {
    const int S = w - 1;
    const int Cw = len - w + 1;

    // ======== phase A: ftab(w) on waves 12..15 || finalize width w-1 on waves 0..3
    if (tid >= 768) {
      const int u = tid - 768;
      if (u < S) {
        const int vd = S - 1 - u;
        const float Gw = Mar[w - 2] + Mar[0];
        double ex = (double)Mar[u] + (double)Mar[vd] - (double)Gw;
        float4 t;
        t.x = __expf((float)ex);
        t.y = __int_as_float(off4[u]);
        t.z = __int_as_float(off4[vd] + u + 1);
        t.w = 0.f;
        ft4[u] = t;
      }
    } else if (w > 2) {
      const int Cp = len - w + 2;               // cells of width w-1
      if (q < ((Cp + 63) >> 6)) {
        const int c = (q << 6) + lane;
        const int WCGp = (Cp <= 64) ? 1 : (Cp <= 128 ? 2 : 4);
        const int WUp = NWAVES / WCGp;
        float mx = 0.f;
        if (c < Cp) {
          float s = 0.f;
          const int base = (c >> 6) * WUp * PSTRIDE + (c & 63);
          for (int k = 0; k < WUp; ++k) s += Part[base + k * PSTRIDE];
          const int dp = w - 2;
          const float corr = (Mar[w - 3] + Mar[0]) - Mar[dp];  // G_{w-1} - Mar[dp]
          const float V = s * __expf(myScore + corr);
          E[off4[dp] + c] = V;
          mx = V;
        }
        #pragma unroll
        for (int o = 1; o < 64; o <<= 1) mx = fmaxf(mx, __shfl_xor(mx, o, 64));
        if (lane == 0) atomicMax(&RmaxU[w - 2], __float_as_uint(mx));
      }
    }
    __syncthreads();

    // ======== phase B: partial sums over u || Mar update || score prefetch
    {
      const int WCG = (Cw <= 64) ? 1 : (Cw <= 128 ? 2 : 4);
      const int lw = (WCG == 1) ? 4 : (WCG == 2) ? 3 : 2;  // log2(WU)
      const int WU = 1 << lw;
      const int cg = q >> lw;
      const int us = q & (WU - 1);
      const int c = (cg << 6) + lane;
      if (c < Cw) {
        float s = 0.f;
        #pragma unroll 4
        for (int u = us; u < S; u += WU) {
          const float4 t = ft4[u];
          s = fmaf(t.x * E[__float_as_int(t.y) + c], E[__float_as_int(t.z) + c], s);
        }
        Part[q * PSTRIDE + (c & 63)] = s;
      }
      // prefetch scores of diag d = w-1 for next phase A's finalize
      if (q < ((Cw + 63) >> 6)) {
        const int cf = (q << 6) + lane;
        if (cf < Cw) {
          const size_t cell = sbase + (size_t)cf * NN + (cf + (w - 1));
          myScore = score_val(slog[cell], sind, cell, run, isbyte);
        }
      }
      if (tid == 0) {
        float lr = __logf(__uint_as_float(RmaxU[w - 2] | 1u));
        lr = fminf(fmaxf(lr, -40.f), 40.f);
        MarD += (double)lr;
        Mar[w - 1] = (float)MarD;
      }
    }
    __syncthreads();
  }

  // ---- finalize width == len (single cell c=0) ----
  if (tid == 0) {
    float ssum = 0.f;
    for (int k = 0; k < NWAVES; ++k) ssum += Part[k * PSTRIDE + 0];
    const float corr = (Mar[len - 2] + Mar[0]) - Mar[len - 1];
    double alpha = (double)Mar[len - 1] + (double)(myScore + corr) + (double)__logf(ssum);
    wsv[run * BB + b] = (float)alpha;
    if (run == 0) wsv[2 * BB + b] = (float)len;
  }
}

extern "C" __global__ void loss_kernel(const float* __restrict__ wsv, float* __restrict__ out) {
  const int t = threadIdx.x;
  float diff = 0.0f, ln = 0.0f;
  if (t < BB) { diff = wsv[BB + t] - wsv[t]; ln = wsv[2 * BB + t]; }
  #pragma unroll
  for (int o = 1; o < 64; o <<= 1) {
    diff += __shfl_xor(diff, o, 64);
    ln += __shfl_xor(ln, o, 64);
  }
  if (t == 0) out[0] = diff / ln;
}

extern "C" void kernel_launch(void* const* d_in, const int* in_sizes, int n_in,
                              void* d_out, int out_size, void* d_ws, size_t ws_size,
                              hipStream_t stream) {
  const float2* slog = (const float2*)d_in[0];
  const void* sind = d_in[1];
  const void* mspan = d_in[2];
  float* wsv = (float*)d_ws;
  cyk_kernel<<<dim3(BB * 2), dim3(NTHREADS), 0, stream>>>(slog, sind, mspan, wsv);
  loss_kernel<<<dim3(1), dim3(64), 0, stream>>>(wsv, (float*)d_out);
}

// Round 4
// 572.930 us; speedup vs baseline: 3.0385x; 1.0941x over previous
//
#include <hip/hip_runtime.h>
#include <hip/hip_bf16.h>
#include <cstdint>
#include <cstddef>

#define NTHREADS 1024
#define NWAVES 16
#define BB 16
#define NN 256
#define EPAD_TOTAL 33280   // sum over d of roundup4(256-d)
#define PSTRIDE 68         // Part row stride (64 + 4 pad)

typedef unsigned char u8;

// Mask arrays may arrive as bool (1 byte), int32, or float32. Detect on
// device: maskspan[0,0,1] == 1 always (lens >= 128). Byte storage -> byte1
// == 1; 4-byte storage -> byte1 == 0 (nonzero int/float bit pattern test).
__device__ __forceinline__ bool mask_val(const void* p, size_t idx, bool isbyte) {
  return isbyte ? (((const u8*)p)[idx] != 0) : (((const int*)p)[idx] != 0);
}

__device__ __forceinline__ float score_val(float2 v, const void* sind, size_t cell,
                                           int run, bool isbyte) {
  if (run == 0) return mask_val(sind, cell, isbyte) ? v.y : v.x;  // ob
  float m = fmaxf(v.x, v.y);                                      // allp
  return m + __logf(1.f + __expf(-fabsf(v.x - v.y)));
}

// prefix of padded diagonal sizes: Fpad(M) = sum_{j=1..M} ((j+3)&~3)
__device__ __forceinline__ int Fpad(int M) {
  int f = M >> 2, r = M & 3;
  return 8*f*f + 8*f + 4*r*(f+1);
}

extern "C" __global__ void __launch_bounds__(NTHREADS, 1)
cyk_kernel(const float2* __restrict__ slog, const void* __restrict__ sind,
           const void* __restrict__ mspan, float* __restrict__ wsv) {
  // Exp-space chart, diagonal-major, each diagonal 16B-aligned.
  // alpha(d,c) = log(E[off4[d]+c]) + Mar[d]; Mar is a deterministic schedule:
  // Mar[d] = Mar[d-1] + log(Rmax[d-1]) (== true max alpha of diag d-1).
  // Inner-loop addresses are strength-reduced: for stride WU (multiple of 4),
  // off4-based operand addresses have constant 2nd difference -WU^2, so the
  // loop carries {aL,dL,aR,dR} in registers: no LDS->address->LDS chains.
  __shared__ __align__(16) float E[EPAD_TOTAL];
  __shared__ float ftab[NN];    // per-width split scale factors
  __shared__ float Mar[NN];
  __shared__ unsigned RmaxU[NN];
  __shared__ int off4[NN + 1];
  __shared__ float Part[NWAVES * PSTRIDE];
  __shared__ float scratch[NWAVES];

  const int b = blockIdx.x >> 1;
  const int run = blockIdx.x & 1;
  const int tid = threadIdx.x;
  const int lane = tid & 63;
  const int q = tid >> 6;
  const bool isbyte = ((const u8*)mspan)[1] != 0;
  const size_t sbase = (size_t)b * (NN * NN);

  // sentence length
  int pred = 0;
  if (tid < NN) pred = mask_val(mspan, sbase + tid, isbyte) ? 1 : 0;
  const int len = __syncthreads_count(pred);

  if (tid <= NN) off4[tid] = Fpad(NN) - Fpad(NN - tid);
  for (int k = tid; k < EPAD_TOTAL; k += NTHREADS) E[k] = 0.f;
  if (tid < NN) RmaxU[tid] = 0u;
  __syncthreads();

  // ---- diagonal 0 ----
  float a0 = -3.0e38f;
  if (tid < len) {
    size_t cell = sbase + (size_t)tid * NN + tid;
    a0 = score_val(slog[cell], sind, cell, run, isbyte);
  }
  float wm = a0;
  #pragma unroll
  for (int o = 1; o < 64; o <<= 1) wm = fmaxf(wm, __shfl_xor(wm, o, 64));
  if (lane == 0) scratch[q] = wm;
  __syncthreads();
  float M0 = scratch[0];
  #pragma unroll
  for (int k = 1; k < NWAVES; ++k) M0 = fmaxf(M0, scratch[k]);
  if (tid < len) E[tid] = __expf(a0 - M0);
  if (tid == 0) { Mar[0] = M0; RmaxU[0] = __float_as_uint(1.0f); }
  double MarD = (double)M0;   // tid0's exact Mar chain
  __syncthreads();

  float myScore = 0.f;        // prefetched span score, carried across phases

  for (int w = 2; w <= len; ++w) {
    const int S = w - 1;
    const int Cw = len - w + 1;

    // ======== phase A: ftab(w) on waves 12..15 || finalize width w-1 on waves 0..3
    if (tid >= 768) {
      const int u = tid - 768;
      if (u < S) {
        const int vd = S - 1 - u;
        const float Gw = Mar[w - 2] + Mar[0];
        double ex = (double)Mar[u] + (double)Mar[vd] - (double)Gw;
        ftab[u] = __expf((float)ex);
      }
    } else if (w > 2) {
      const int Cp = len - w + 2;               // cells of width w-1
      if (q < ((Cp + 63) >> 6)) {
        const int c = (q << 6) + lane;
        const int WCGp = (Cp <= 64) ? 1 : (Cp <= 128 ? 2 : 4);
        const int WUp = NWAVES / WCGp;
        float mx = 0.f;
        if (c < Cp) {
          float s = 0.f;
          const int base = (c >> 6) * WUp * PSTRIDE + (c & 63);
          for (int k = 0; k < WUp; ++k) s += Part[base + k * PSTRIDE];
          const int dp = w - 2;
          const float corr = (Mar[w - 3] + Mar[0]) - Mar[dp];  // G_{w-1} - Mar[dp]
          const float V = s * __expf(myScore + corr);
          E[off4[dp] + c] = V;
          mx = V;
        }
        #pragma unroll
        for (int o = 1; o < 64; o <<= 1) mx = fmaxf(mx, __shfl_xor(mx, o, 64));
        if (lane == 0) atomicMax(&RmaxU[w - 2], __float_as_uint(mx));
      }
    }
    __syncthreads();

    // ======== phase B: partial sums over u || Mar update || score prefetch
    {
      const int WCG = (Cw <= 64) ? 1 : (Cw <= 128 ? 2 : 4);
      const int lw = (WCG == 1) ? 4 : (WCG == 2) ? 3 : 2;  // log2(WU)
      const int WU = 1 << lw;
      const int WU2 = WU * WU;
      const int cg = q >> lw;
      const int us = q & (WU - 1);
      const int c = (cg << 6) + lane;
      if (c < Cw) {
        float s = 0.f;
        if (us < S) {
          const int vd0 = S - 1 - us;
          int aL = off4[us] + c;
          int aR = off4[vd0] + us + 1 + c;
          // dL(u) = WU*(256-u) - WU*(WU-1)/2 + 3*WU/2 ; d(dL) = -WU^2
          int dL = WU * (256 - us) - (WU * (WU - 1)) / 2 + (3 * WU) / 2;
          // dR(u) = -256*WU + WU*vd - WU^2 + WU*(WU-1)/2 - 3*WU/2 + WU ; d(dR) = -WU^2
          int dR = -256 * WU + WU * vd0 - WU2 + (WU * (WU - 1)) / 2 - (3 * WU) / 2 + WU;
          #pragma unroll 8
          for (int u = us; u < S; u += WU) {
            const float f = ftab[u];
            s = fmaf(f * E[aL], E[aR], s);
            aL += dL; dL -= WU2;
            aR += dR; dR -= WU2;
          }
        }
        Part[q * PSTRIDE + (c & 63)] = s;
      }
      // prefetch scores of diag d = w-1 for next phase A's finalize
      if (q < ((Cw + 63) >> 6)) {
        const int cf = (q << 6) + lane;
        if (cf < Cw) {
          const size_t cell = sbase + (size_t)cf * NN + (cf + (w - 1));
          myScore = score_val(slog[cell], sind, cell, run, isbyte);
        }
      }
      if (tid == 0) {
        float lr = __logf(__uint_as_float(RmaxU[w - 2] | 1u));
        lr = fminf(fmaxf(lr, -40.f), 40.f);
        MarD += (double)lr;
        Mar[w - 1] = (float)MarD;
      }
    }
    __syncthreads();
  }

  // ---- finalize width == len (single cell c=0) ----
  if (tid == 0) {
    float ssum = 0.f;
    for (int k = 0; k < NWAVES; ++k) ssum += Part[k * PSTRIDE + 0];
    const float corr = (Mar[len - 2] + Mar[0]) - Mar[len - 1];
    double alpha = (double)Mar[len - 1] + (double)(myScore + corr) + (double)__logf(ssum);
    wsv[run * BB + b] = (float)alpha;
    if (run == 0) wsv[2 * BB + b] = (float)len;
  }
}

extern "C" __global__ void loss_kernel(const float* __restrict__ wsv, float* __restrict__ out) {
  const int t = threadIdx.x;
  float diff = 0.0f, ln = 0.0f;
  if (t < BB) { diff = wsv[BB + t] - wsv[t]; ln = wsv[2 * BB + t]; }
  #pragma unroll
  for (int o = 1; o < 64; o <<= 1) {
    diff += __shfl_xor(diff, o, 64);
    ln += __shfl_xor(ln, o, 64);
  }
  if (t == 0) out[0] = diff / ln;
}

extern "C" void kernel_launch(void* const* d_in, const int* in_sizes, int n_in,
                              void* d_out, int out_size, void* d_ws, size_t ws_size,
                              hipStream_t stream) {
  const float2* slog = (const float2*)d_in[0];
  const void* sind = d_in[1];
  const void* mspan = d_in[2];
  float* wsv = (float*)d_ws;
  cyk_kernel<<<dim3(BB * 2), dim3(NTHREADS), 0, stream>>>(slog, sind, mspan, wsv);
  loss_kernel<<<dim3(1), dim3(64), 0, stream>>>(wsv, (float*)d_out);
}